// Round 12
// baseline (250.502 us; speedup 1.0000x reference)
//
#include <hip/hip_runtime.h>
#include <hip/hip_bf16.h>

// Renderer vertex-normals rev12. Math FROZEN from rev8 (passing, absmax = 1 bf16 ulp):
//   cross: c_i = fmaf(a_p, b_q, -pinned(a_q*b_p))  (uniform LHS fusion)
//   norms: (x*x + y*y) + z*z, sqrtf, fmaxf(n,1e-12f), IEEE '/'
//   vertex sum: c = 0..5 sequential; default hipcc contraction elsewhere (as R8)
// Rev12 = batch-contiguous fn layout (layout/scheduling only):
//   fnT is (F, bs): for one (v,c) the 32 batches are 512 contiguous bytes.
//   Vertex pass maps lane%32 -> batch: wave gathers are dense 512 B runs
//   (8 fully-used lines) instead of 32 random 16 B-in-64 B lines. R10/R11's
//   4x over-fetch (275 MB vs 92) was line-utilization + table-sweep drift,
//   not stream pollution (R11 nt hints: no change -> reverted).
// bs=32, V=65536, F=130050, C=6.

#define XCDS 8

__device__ __forceinline__ float mulf_pin(float a, float b) {
  float t = a * b;
  asm("" : "+v"(t));   // pin: separately-rounded f32 product, cannot re-fuse
  return t;
}

__device__ __forceinline__ float3 cross_lhs(float ax, float ay, float az,
                                            float bx, float by, float bz) {
  float cx = __builtin_fmaf(ay, bz, -mulf_pin(az, by));
  float cy = __builtin_fmaf(az, bx, -mulf_pin(ax, bz));
  float cz = __builtin_fmaf(ax, by, -mulf_pin(ay, bx));
  return make_float3(cx, cy, cz);
}

// ---------------- Kernel A: pack points into float4 (coalesced) ------------
__global__ __launch_bounds__(256) void rend12_pack(
    const float* __restrict__ points,   // (bs, 3, V)
    float4*      __restrict__ pts4,     // (bs, V)
    int V) {
  int v = blockIdx.x * blockDim.x + threadIdx.x;
  int b = blockIdx.y;
  const float* pb = points + (size_t)b * 3 * V;
  pts4[(size_t)b * V + v] = make_float4(pb[v], pb[V + v], pb[2 * V + v], 0.0f);
}

// ---------------- Kernel B: face normals, XCD-partitioned, fnT output ------
// grid.x = XCDS * fpb. Thread loads its 3 indices once, loops its XCD's bpx
// batches (pts4 tables hot in that XCD's L2). Writes fnT[f*bs + b]: one
// XCD's 4 batches fill one aligned 64 B line per face.
__global__ __launch_bounds__(256) void rend12_face(
    const float4* __restrict__ pts4,    // (bs, V)
    const int*    __restrict__ faces,   // (F, 3)
    float4*       __restrict__ fnT,     // (F, bs)  batch-inner
    int F, int V, int bpx, int bs) {
  int xcd = blockIdx.x % XCDS;
  int seq = blockIdx.x / XCDS;
  int f   = seq * 256 + threadIdx.x;
  if (f >= F) return;

  int i0 = faces[3 * f + 0];
  int i1 = faces[3 * f + 1];
  int i2 = faces[3 * f + 2];

  for (int bl = 0; bl < bpx; ++bl) {
    int b = xcd * bpx + bl;
    const float4* P = pts4 + (size_t)b * V;
    float4 p0 = P[i0];
    float4 p1 = P[i1];
    float4 p2 = P[i2];

    float ax = p1.x - p0.x, ay = p1.y - p0.y, az = p1.z - p0.z;
    float bx = p2.x - p0.x, by = p2.y - p0.y, bz = p2.z - p0.z;

    float3 c = cross_lhs(ax, ay, az, bx, by, bz);

    float n = sqrtf((c.x * c.x + c.y * c.y) + c.z * c.z);
    float d = fmaxf(n, 1e-12f);

    fnT[(size_t)f * bs + b] = make_float4(c.x / d, c.y / d, c.z / d, 0.0f);
  }
}

// ---------------- Kernel C: vertex normals, batch-contiguous gathers -------
// lane%32 = batch. Group of 32 lanes processes VPG consecutive vertices; per
// (v,c) the group's gather is 512 contiguous bytes. vti/vtw are wave-uniform
// broadcast loads. Sum order c=0..5 per (v,b): frozen.
#define VPG 8
__global__ __launch_bounds__(256) void rend12_vertex(
    const float4* __restrict__ fnT,     // (F, bs)
    const int*    __restrict__ vti,     // (V, 6)
    const float*  __restrict__ vtw,     // (V, 6)
    float*        __restrict__ out,     // (bs, V, 3)
    int F, int V, int bs) {
  int b     = threadIdx.x & 31;         // batch = lane%32
  int group = threadIdx.x >> 5;         // 8 groups per block
  int v0    = (blockIdx.x * 8 + group) * VPG;

  for (int k = 0; k < VPG; ++k) {
    int v = v0 + k;

    float sx = 0.f, sy = 0.f, sz = 0.f;
#pragma unroll
    for (int c = 0; c < 6; ++c) {       // sequential c-order (frozen)
      int   idx = vti[(size_t)v * 6 + c];   // uniform across group: broadcast
      float w   = vtw[(size_t)v * 6 + c];
      float4 nr = fnT[(size_t)idx * bs + b];  // dense 512 B per group
      sx += nr.x * w;
      sy += nr.y * w;
      sz += nr.z * w;
    }

    float n = sqrtf((sx * sx + sy * sy) + sz * sz);
    float d = fmaxf(n, 1e-12f);

    size_t o = ((size_t)b * V + v) * 3;
    out[o + 0] = sx / d;
    out[o + 1] = sy / d;
    out[o + 2] = sz / d;
  }
}

// ================= Fallback path (rev8, proven): ===========================
__global__ __launch_bounds__(256) void rend12_face_fb(
    const float* __restrict__ points,
    const int*   __restrict__ faces,
    float4*      __restrict__ fnorm,    // (bs, F)
    int F, int V) {
  int f = blockIdx.x * blockDim.x + threadIdx.x;
  int b = blockIdx.y;
  if (f >= F) return;

  int i0 = faces[3 * f + 0];
  int i1 = faces[3 * f + 1];
  int i2 = faces[3 * f + 2];

  const float* pb = points + (size_t)b * 3 * V;
  float ax = pb[i1] - pb[i0], ay = pb[V + i1] - pb[V + i0], az = pb[2 * V + i1] - pb[2 * V + i0];
  float bx = pb[i2] - pb[i0], by = pb[V + i2] - pb[V + i0], bz = pb[2 * V + i2] - pb[2 * V + i0];

  float3 c = cross_lhs(ax, ay, az, bx, by, bz);

  float n = sqrtf((c.x * c.x + c.y * c.y) + c.z * c.z);
  float d = fmaxf(n, 1e-12f);

  fnorm[(size_t)b * F + f] = make_float4(c.x / d, c.y / d, c.z / d, 0.0f);
}

__global__ __launch_bounds__(256) void rend12_vertex_fb(
    const float4* __restrict__ fnorm,   // (bs, F)
    const int*    __restrict__ vti,
    const float*  __restrict__ vtw,
    float*        __restrict__ out,
    int F, int V) {
  int v = blockIdx.x * blockDim.x + threadIdx.x;
  int b = blockIdx.y;
  if (v >= V) return;

  const float4* fb = fnorm + (size_t)b * F;
  float sx = 0.f, sy = 0.f, sz = 0.f;
#pragma unroll
  for (int c = 0; c < 6; ++c) {
    int    idx = vti[v * 6 + c];
    float  w   = vtw[v * 6 + c];
    float4 nr  = fb[idx];
    sx += nr.x * w;
    sy += nr.y * w;
    sz += nr.z * w;
  }
  float n = sqrtf((sx * sx + sy * sy) + sz * sz);
  float d = fmaxf(n, 1e-12f);
  size_t o = ((size_t)b * V + v) * 3;
  out[o + 0] = sx / d;
  out[o + 1] = sy / d;
  out[o + 2] = sz / d;
}

extern "C" void kernel_launch(void* const* d_in, const int* in_sizes, int n_in,
                              void* d_out, int out_size, void* d_ws, size_t ws_size,
                              hipStream_t stream) {
  const float* points = (const float*)d_in[0];
  const int*   faces  = (const int*)d_in[1];
  const int*   vti    = (const int*)d_in[2];
  const float* vtw    = (const float*)d_in[3];
  float*       out    = (float*)d_out;

  const int F  = in_sizes[1] / 3;                       // 130050
  const int V  = in_sizes[2] / 6;                       // 65536
  const int bs = (int)(in_sizes[0] / (3 * (size_t)V));  // 32

  const size_t pts4_bytes = (size_t)bs * V * sizeof(float4);  // 33.6 MB
  const size_t fn_bytes   = (size_t)bs * F * sizeof(float4);  // 66.6 MB

  const bool fast_ok = (ws_size >= pts4_bytes + fn_bytes) &&
                       (bs == 32) && (V % (8 * VPG * 256 / 32) == 0);

  if (fast_ok) {
    float4* pts4 = (float4*)d_ws;
    float4* fnT  = (float4*)((char*)d_ws + pts4_bytes);
    const int bpx = bs / XCDS;                 // 4 batches per XCD
    const int fpb = (F + 255) / 256;           // 509 face-blocks per batch

    rend12_pack<<<dim3(V / 256, bs), dim3(256), 0, stream>>>(points, pts4, V);
    rend12_face<<<dim3(XCDS * fpb), dim3(256), 0, stream>>>(
        pts4, faces, fnT, F, V, bpx, bs);
    // block = 8 groups x 32 lanes; each group does VPG vertices
    rend12_vertex<<<dim3(V / (8 * VPG)), dim3(256), 0, stream>>>(
        fnT, vti, vtw, out, F, V, bs);
  } else if (ws_size >= fn_bytes) {  // rev8 fallback
    float4* fnorm = (float4*)d_ws;
    rend12_face_fb<<<dim3((F + 255) / 256, bs), dim3(256), 0, stream>>>(
        points, faces, fnorm, F, V);
    rend12_vertex_fb<<<dim3((V + 255) / 256, bs), dim3(256), 0, stream>>>(
        fnorm, vti, vtw, out, F, V);
  }
}

// Round 13
// 228.898 us; speedup vs baseline: 1.0944x; 1.0944x over previous
//
#include <hip/hip_runtime.h>
#include <hip/hip_bf16.h>

// Renderer vertex-normals rev13. Math FROZEN from rev8 (passing, absmax = 1 bf16 ulp):
//   cross: c_i = fmaf(a_p, b_q, -pinned(a_q*b_p))  (uniform LHS fusion)
//   norms: (x*x + y*y) + z*z, sqrtf, fmaxf(n,1e-12f), IEEE '/'
//   vertex sum: sx += nr.x*w, c = 0..5 sequential (default contraction, as rev8)
// Rev13 = TEMPORAL batch phasing (layout/scheduling only):
//   R9-R12 all kept >=4 gather tables live per XCD (>4MB L2) -> permanent
//   thrash at the ~3.4 TB/s random-line ceiling. Now the batch loop is
//   innermost per thread; all blocks co-resident sweep b=0..31 in lockstep,
//   so chip-wide only ~1 table (pts4: 1.05 MB / fn: 2.08 MB) is hot at a
//   time and fits every XCD's L2. Indices/weights live in registers (read
//   once). All stores coalesced: fn is (bs,F), out per-wave 768 B runs.
// bs=32, V=65536, F=130050, C=6.

__device__ __forceinline__ float mulf_pin(float a, float b) {
  float t = a * b;
  asm("" : "+v"(t));   // pin: separately-rounded f32 product, cannot re-fuse
  return t;
}

__device__ __forceinline__ float3 cross_lhs(float ax, float ay, float az,
                                            float bx, float by, float bz) {
  float cx = __builtin_fmaf(ay, bz, -mulf_pin(az, by));
  float cy = __builtin_fmaf(az, bx, -mulf_pin(ax, bz));
  float cz = __builtin_fmaf(ax, by, -mulf_pin(ay, bx));
  return make_float3(cx, cy, cz);
}

// ---------------- Kernel A: pack points into float4 (coalesced) ------------
__global__ __launch_bounds__(256) void rend13_pack(
    const float* __restrict__ points,   // (bs, 3, V)
    float4*      __restrict__ pts4,     // (bs, V)
    int V) {
  int v = blockIdx.x * blockDim.x + threadIdx.x;
  int b = blockIdx.y;
  const float* pb = points + (size_t)b * 3 * V;
  pts4[(size_t)b * V + v] = make_float4(pb[v], pb[V + v], pb[2 * V + v], 0.0f);
}

// ---------------- Kernel B: face normals, batch-phase sweep ----------------
// One thread per face; indices in registers; inner loop over all batches.
// Co-resident blocks sweep batches in lockstep -> pts4 table b (~1.05 MB)
// is the only hot gather set chip-wide. fn (bs,F) writes: wave = 64
// consecutive f, fixed b -> 1 KB contiguous.
__global__ __launch_bounds__(128) void rend13_face(
    const float4* __restrict__ pts4,    // (bs, V)
    const int*    __restrict__ faces,   // (F, 3)
    float4*       __restrict__ fnorm,   // (bs, F)
    int F, int V, int bs) {
  int f = blockIdx.x * blockDim.x + threadIdx.x;
  if (f >= F) return;

  int i0 = faces[3 * f + 0];
  int i1 = faces[3 * f + 1];
  int i2 = faces[3 * f + 2];

  for (int b = 0; b < bs; ++b) {        // temporal phase = batch
    const float4* P = pts4 + (size_t)b * V;
    float4 p0 = P[i0];
    float4 p1 = P[i1];
    float4 p2 = P[i2];

    float ax = p1.x - p0.x, ay = p1.y - p0.y, az = p1.z - p0.z;
    float bx = p2.x - p0.x, by = p2.y - p0.y, bz = p2.z - p0.z;

    float3 c = cross_lhs(ax, ay, az, bx, by, bz);

    float n2 = (c.x * c.x + c.y * c.y) + c.z * c.z;
    float n  = sqrtf(n2);
    float d  = fmaxf(n, 1e-12f);

    fnorm[(size_t)b * F + f] = make_float4(c.x / d, c.y / d, c.z / d, 0.0f);
  }
}

// ---------------- Kernel C: vertex normals, batch-phase sweep --------------
// One thread per vertex; vti/vtw in registers; inner loop over batches.
// fn table b (2.08 MB) is the hot set per phase. out: wave = 64 consecutive
// v, fixed b -> 768 B contiguous.
__global__ __launch_bounds__(128) void rend13_vertex(
    const float4* __restrict__ fnorm,   // (bs, F)
    const int*    __restrict__ vti,     // (V, 6)
    const float*  __restrict__ vtw,     // (V, 6)
    float*        __restrict__ out,     // (bs, V, 3)
    int F, int V, int bs) {
  int v = blockIdx.x * blockDim.x + threadIdx.x;
  if (v >= V) return;

  const int2*   t2 = (const int2*)(vti + (size_t)v * 6);
  const float2* w2 = (const float2*)(vtw + (size_t)v * 6);
  int2   t01 = t2[0], t23 = t2[1], t45 = t2[2];
  float2 w01 = w2[0], w23 = w2[1], w45 = w2[2];
  int   idx[6] = {t01.x, t01.y, t23.x, t23.y, t45.x, t45.y};
  float wgt[6] = {w01.x, w01.y, w23.x, w23.y, w45.x, w45.y};

  for (int b = 0; b < bs; ++b) {        // temporal phase = batch
    const float4* FN = fnorm + (size_t)b * F;

    float sx = 0.f, sy = 0.f, sz = 0.f;
#pragma unroll
    for (int c = 0; c < 6; ++c) {       // sequential c-order (frozen)
      float4 nr = FN[idx[c]];
      sx += nr.x * wgt[c];
      sy += nr.y * wgt[c];
      sz += nr.z * wgt[c];
    }

    float n = sqrtf((sx * sx + sy * sy) + sz * sz);
    float d = fmaxf(n, 1e-12f);

    size_t o = ((size_t)b * V + v) * 3;
    out[o + 0] = sx / d;
    out[o + 1] = sy / d;
    out[o + 2] = sz / d;
  }
}

// ================= Fallback path (rev8, proven): ===========================
__global__ __launch_bounds__(256) void rend13_face_fb(
    const float* __restrict__ points,
    const int*   __restrict__ faces,
    float4*      __restrict__ fnorm,    // (bs, F)
    int F, int V) {
  int f = blockIdx.x * blockDim.x + threadIdx.x;
  int b = blockIdx.y;
  if (f >= F) return;

  int i0 = faces[3 * f + 0];
  int i1 = faces[3 * f + 1];
  int i2 = faces[3 * f + 2];

  const float* pb = points + (size_t)b * 3 * V;
  float ax = pb[i1] - pb[i0], ay = pb[V + i1] - pb[V + i0], az = pb[2 * V + i1] - pb[2 * V + i0];
  float bx = pb[i2] - pb[i0], by = pb[V + i2] - pb[V + i0], bz = pb[2 * V + i2] - pb[2 * V + i0];

  float3 c = cross_lhs(ax, ay, az, bx, by, bz);

  float n = sqrtf((c.x * c.x + c.y * c.y) + c.z * c.z);
  float d = fmaxf(n, 1e-12f);

  fnorm[(size_t)b * F + f] = make_float4(c.x / d, c.y / d, c.z / d, 0.0f);
}

__global__ __launch_bounds__(256) void rend13_vertex_fb(
    const float4* __restrict__ fnorm,   // (bs, F)
    const int*    __restrict__ vti,
    const float*  __restrict__ vtw,
    float*        __restrict__ out,
    int F, int V) {
  int v = blockIdx.x * blockDim.x + threadIdx.x;
  int b = blockIdx.y;
  if (v >= V) return;

  const float4* fb = fnorm + (size_t)b * F;
  float sx = 0.f, sy = 0.f, sz = 0.f;
#pragma unroll
  for (int c = 0; c < 6; ++c) {
    int    idx = vti[v * 6 + c];
    float  w   = vtw[v * 6 + c];
    float4 nr  = fb[idx];
    sx += nr.x * w;
    sy += nr.y * w;
    sz += nr.z * w;
  }
  float n = sqrtf((sx * sx + sy * sy) + sz * sz);
  float d = fmaxf(n, 1e-12f);
  size_t o = ((size_t)b * V + v) * 3;
  out[o + 0] = sx / d;
  out[o + 1] = sy / d;
  out[o + 2] = sz / d;
}

extern "C" void kernel_launch(void* const* d_in, const int* in_sizes, int n_in,
                              void* d_out, int out_size, void* d_ws, size_t ws_size,
                              hipStream_t stream) {
  const float* points = (const float*)d_in[0];
  const int*   faces  = (const int*)d_in[1];
  const int*   vti    = (const int*)d_in[2];
  const float* vtw    = (const float*)d_in[3];
  float*       out    = (float*)d_out;

  const int F  = in_sizes[1] / 3;                       // 130050
  const int V  = in_sizes[2] / 6;                       // 65536
  const int bs = (int)(in_sizes[0] / (3 * (size_t)V));  // 32

  const size_t pts4_bytes = (size_t)bs * V * sizeof(float4);  // 33.6 MB
  const size_t fn_bytes   = (size_t)bs * F * sizeof(float4);  // 66.6 MB

  const bool fast_ok = (ws_size >= pts4_bytes + fn_bytes) && (V % 256 == 0);

  if (fast_ok) {
    float4* pts4  = (float4*)d_ws;
    float4* fnorm = (float4*)((char*)d_ws + pts4_bytes);

    rend13_pack<<<dim3(V / 256, bs), dim3(256), 0, stream>>>(points, pts4, V);
    rend13_face<<<dim3((F + 127) / 128), dim3(128), 0, stream>>>(
        pts4, faces, fnorm, F, V, bs);
    rend13_vertex<<<dim3((V + 127) / 128), dim3(128), 0, stream>>>(
        fnorm, vti, vtw, out, F, V, bs);
  } else if (ws_size >= fn_bytes) {  // rev8 fallback
    float4* fnorm = (float4*)d_ws;
    rend13_face_fb<<<dim3((F + 255) / 256, bs), dim3(256), 0, stream>>>(
        points, faces, fnorm, F, V);
    rend13_vertex_fb<<<dim3((V + 255) / 256, bs), dim3(256), 0, stream>>>(
        fnorm, vti, vtw, out, F, V);
  }
}